// Round 10
// baseline (358.083 us; speedup 1.0000x reference)
//
#include <hip/hip_runtime.h>
#include <math.h>

// Problem constants (from reference)
#define LL   2048     // seq len
#define BB   64       // batch
#define EE   256      // embedding
#define HH   128      // lstm hidden per dir
#define GG   512      // 4*H gates
#define TT   128      // utterances (L / SEP_EVERY)
#define SEPT 50256

// ---------------------------------------------------------------------------
// Kernel 1: per-column prefix-scan of SEP flags -> seg[t,b], plus per-(utt,b)
// token counts and start offsets (segments are contiguous per column).
// ---------------------------------------------------------------------------
__global__ __launch_bounds__(256) void segscan_k(
    const int* __restrict__ x, int* __restrict__ seg,
    int* __restrict__ cnt, int* __restrict__ start)
{
    int b   = blockIdx.x;    // 0..63
    int tid = threadIdx.x;   // 0..255, 8 tokens each
    __shared__ int tsum[256];
    __shared__ int ucnt[TT];
    __shared__ int ustart[TT];

    int flags[8];
    int local = 0;
#pragma unroll
    for (int i = 0; i < 8; i++) {
        int t = tid * 8 + i;
        flags[i] = (x[t * BB + b] == SEPT) ? 1 : 0;
        local += flags[i];
    }
    tsum[tid] = local;
    __syncthreads();
    int val = local;
    for (int off = 1; off < 256; off <<= 1) {
        int other = (tid >= off) ? tsum[tid - off] : 0;
        __syncthreads();
        val += other;
        tsum[tid] = val;
        __syncthreads();
    }
    int excl = val - local;   // seps strictly before this thread's chunk

    if (tid < TT) ucnt[tid] = 0;
    __syncthreads();
    int run = excl;
#pragma unroll
    for (int i = 0; i < 8; i++) {
        int t = tid * 8 + i;
        int s = run;                 // seg id = #seps before this token
        seg[t * BB + b] = s;
        run += flags[i];
        if (s < TT) atomicAdd(&ucnt[s], 1);
    }
    __syncthreads();
    if (tid == 0) {
        int acc = 0;
        for (int u = 0; u < TT; u++) { ustart[u] = acc; acc += ucnt[u]; }
    }
    __syncthreads();
    if (tid < TT) {
        cnt[tid * BB + b]   = ucnt[tid];
        start[tid * BB + b] = ustart[tid];
    }
}

// ---------------------------------------------------------------------------
// Kernel 2: embedding gather + mean pool. One WAVE per (utt,b); lane holds a
// float4 column slice -> one coalesced 1KB row read per token. Grid = 2048.
// ---------------------------------------------------------------------------
__global__ __launch_bounds__(256) void pool_k(
    const int* __restrict__ x, const float* __restrict__ emb,
    const int* __restrict__ cnt, const int* __restrict__ start,
    float* __restrict__ up)
{
    int wid  = threadIdx.x >> 6;
    int lane = threadIdx.x & 63;
    int bid  = blockIdx.x * 4 + wid;   // u*64+b, bid in [0,8192)
    int b    = bid & 63;
    int c    = cnt[bid];
    int st   = start[bid];

    float4 acc = {0.f, 0.f, 0.f, 0.f};
    int tok = (c > 0) ? x[st * BB + b] : 0;
    for (int j = 0; j < c; j++) {
        int tok_n = (j + 1 < c) ? x[(st + j + 1) * BB + b] : 0;  // prefetch
        float4 v = ((const float4*)(emb + (size_t)tok * EE))[lane];
        acc.x += v.x; acc.y += v.y; acc.z += v.z; acc.w += v.w;
        tok = tok_n;
    }
    float inv = (c > 0) ? 1.f / (float)c : 0.f;
    float4 r = {acc.x * inv, acc.y * inv, acc.z * inv, acc.w * inv};
    ((float4*)(up + (size_t)bid * EE))[lane] = r;
}

// ---------------------------------------------------------------------------
// Kernel 3: xp = u @ W_cat^T + (b_ih + b_hh).  fp32 register-tiled GEMM.
// ---------------------------------------------------------------------------
__global__ __launch_bounds__(256) void xp_gemm_k(
    const float* __restrict__ A,
    const float* __restrict__ wf, const float* __restrict__ wb,
    const float* __restrict__ bihf, const float* __restrict__ bhhf,
    const float* __restrict__ bihb, const float* __restrict__ bhhb,
    float* __restrict__ C)
{
    __shared__ float As[32][64];    // [k][m]
    __shared__ float Bs[32][64];    // [k][n]
    int tid  = threadIdx.x;
    int row0 = blockIdx.x * 64;     // 128 blocks
    int col0 = blockIdx.y * 64;     // 16 blocks
    int tx = tid & 15, ty = tid >> 4;
    float acc[4][4] = {};

    for (int k0 = 0; k0 < EE; k0 += 32) {
#pragma unroll
        for (int i = 0; i < 2; i++) {
            int idx = tid + i * 256;       // float4 slot
            int m   = idx >> 3;
            int k4  = idx & 7;
            float4 av = *(const float4*)(A + (size_t)(row0 + m) * EE + k0 + k4 * 4);
            As[k4 * 4 + 0][m] = av.x; As[k4 * 4 + 1][m] = av.y;
            As[k4 * 4 + 2][m] = av.z; As[k4 * 4 + 3][m] = av.w;
        }
#pragma unroll
        for (int i = 0; i < 2; i++) {
            int idx = tid + i * 256;
            int n   = idx >> 3;
            int k4  = idx & 7;
            int gc  = col0 + n;
            const float* wsrc = (gc < GG) ? (wf + (size_t)gc * EE)
                                          : (wb + (size_t)(gc - GG) * EE);
            float4 bv = *(const float4*)(wsrc + k0 + k4 * 4);
            Bs[k4 * 4 + 0][n] = bv.x; Bs[k4 * 4 + 1][n] = bv.y;
            Bs[k4 * 4 + 2][n] = bv.z; Bs[k4 * 4 + 3][n] = bv.w;
        }
        __syncthreads();
#pragma unroll
        for (int k = 0; k < 32; k++) {
            float a4[4], b4[4];
            *(float4*)a4 = *(const float4*)&As[k][ty * 4];
            *(float4*)b4 = *(const float4*)&Bs[k][tx * 4];
#pragma unroll
            for (int i = 0; i < 4; i++)
#pragma unroll
                for (int j = 0; j < 4; j++)
                    acc[i][j] += a4[i] * b4[j];
        }
        __syncthreads();
    }
#pragma unroll
    for (int i = 0; i < 4; i++) {
        int r = row0 + ty * 4 + i;
#pragma unroll
        for (int j = 0; j < 4; j++) {
            int gc = col0 + tx * 4 + j;
            float bias = (gc < GG) ? (bihf[gc] + bhhf[gc])
                                   : (bihb[gc - GG] + bhhb[gc - GG]);
            C[(size_t)r * 1024 + gc] = acc[i][j] + bias;
        }
    }
}

// ---------------------------------------------------------------------------
// Fast activations
// ---------------------------------------------------------------------------
__device__ __forceinline__ float sigm_f(float x) {
    return 1.f / (1.f + __expf(-x));
}
__device__ __forceinline__ float tanh_f(float x) {
    return 1.f - 2.f / (__expf(2.f * x) + 1.f);
}

// ---------------------------------------------------------------------------
// Kernel 4: LSTM recurrence, v7 = v6 + VOLATILE weight loads.
//
// r1-r9 saga: plateau at 129-131 us = per-XCD L2 BW wall. The weight loads
// are invariant (const __restrict__) hence REMATERIALIZABLE; the pre-RA
// scheduler sinks them into the K-loop no matter the occupancy target
// (r9 proved it: 82 KB LDS -> 1 blk/CU, 256-reg budget, VGPR still 88).
// Sunk loads re-read 256 KB/CU/step from L2: 16 blks/XCD on ~4.3 TB/s
// per-XCD L2 = ~2340 cyc/step = 125 us — matches every measurement.
//
// Fix: VOLATILE loads. A volatile load must execute exactly once in source
// order — duplicating it into a loop is illegal, a hard semantic guarantee
// (unlike asm pins / occupancy attrs, both defeated r2-r9). Values must
// then stay live across the loop; 82 KB LDS + waves_per_eu(2,2) gives a
// 256-reg/wave unified budget, ~180 live regs fit (worst case RA uses
// AGPR spills — still register-speed). One-time cost: 128 scalar loads
// per thread touching 8 L1-cached lines. Residual floor ~1000 cyc/step
// (512 FMA-issue + barrier + phase-2 chain) -> ~55-70 us predicted.
// ---------------------------------------------------------------------------
#define PSTR 1280
__global__ __launch_bounds__(512)
__attribute__((amdgpu_waves_per_eu(2, 2)))
void lstm_rec_k(
    const float* __restrict__ xp,            // [T*B][1024]
    const float* __restrict__ whh_f, const float* __restrict__ whh_b,
    float* __restrict__ hout)                // [2][T][B][H]
{
    int bid = blockIdx.x;
    int dir = bid >> 6;
    int b   = bid & 63;
    int tid = threadIdx.x;
    int wv  = tid >> 6;      // wave id 0..7 -> k-slice and unit-slice
    int l   = tid & 63;
    const float* whh = dir ? whh_b : whh_f;

    // weights: wreg[j][k] = whh[(l+64j)*128 + 16wv + k], 128 floats/thread.
    // VOLATILE: cannot be rematerialized/sunk into the loop (see header).
    float wreg[8][16];
#pragma unroll
    for (int j = 0; j < 8; j++) {
        const volatile float* src = whh + (size_t)(l + 64 * j) * HH + 16 * wv;
#pragma unroll
        for (int k = 0; k < 16; k++)
            wreg[j][k] = src[k];
    }

    __shared__ __align__(16) float h_lds[HH];      // wave w: [16w,16w+16)
    __shared__ float part[2][8][PSTR];             // 80 KB: pad forces 1 blk/CU

    int t_type = l >> 4;          // 0:i 1:f 2:g 3:o
    int u16    = l & 15;
    int unit   = 16 * wv + u16;
    int g2     = t_type * 128 + unit;              // gate reduced in phase 2
    int phys2  = t_type * 128 + ((unit + 8 * t_type) & 127);

    // phase-1 write indices (swizzled), g = l + 64j
    int physw[8];
#pragma unroll
    for (int j = 0; j < 8; j++) {
        int t = j >> 1;
        physw[j] = t * 128 + ((64 * (j & 1) + l + 8 * t) & 127);
    }

    float c = 0.f;                                 // valid in t_type==0 lanes
    if (l < 16) h_lds[unit] = 0.f;
    __syncthreads();

    int t0   = dir ? (TT - 1) : 0;
    float xg = xp[(size_t)(t0 * BB + b) * 1024 + dir * GG + g2];

    for (int s = 0; s < TT; s++) {
        int p = s & 1;
        // ---- phase 1: partial dots over own k-slice (wave-private h) ----
        float hs[16];
        *(float4*)&hs[0]  = *(const float4*)&h_lds[16 * wv + 0];
        *(float4*)&hs[4]  = *(const float4*)&h_lds[16 * wv + 4];
        *(float4*)&hs[8]  = *(const float4*)&h_lds[16 * wv + 8];
        *(float4*)&hs[12] = *(const float4*)&h_lds[16 * wv + 12];

#pragma unroll
        for (int j = 0; j < 8; j++) {
            float a0 = 0.f, a1 = 0.f, a2 = 0.f, a3 = 0.f;
#pragma unroll
            for (int k4 = 0; k4 < 4; k4++) {
                a0 += wreg[j][k4 * 4 + 0] * hs[k4 * 4 + 0];
                a1 += wreg[j][k4 * 4 + 1] * hs[k4 * 4 + 1];
                a2 += wreg[j][k4 * 4 + 2] * hs[k4 * 4 + 2];
                a3 += wreg[j][k4 * 4 + 3] * hs[k4 * 4 + 3];
            }
            part[p][wv][physw[j]] = (a0 + a1) + (a2 + a3);
        }

        // prefetch next step's xp while FMAs drain
        float xg_next = xg;
        if (s < TT - 1) {
            int tn = dir ? (TT - 2 - s) : (s + 1);
            xg_next = xp[(size_t)(tn * BB + b) * 1024 + dir * GG + g2];
        }
        __syncthreads();

        // ---- phase 2: reduce gate g2, activate, combine, update ----
        float sum = xg;
#pragma unroll
        for (int w2i = 0; w2i < 8; w2i++)
            sum += part[p][w2i][phys2];

        bool is_g = (t_type == 2);
        float e  = __expf(is_g ? (2.f * sum) : (-sum));
        float av = is_g ? (1.f - 2.f / (e + 1.f)) : (1.f / (1.f + e));

        float r1 = __shfl_xor(av, 16);   // t0 lanes: sig(f)
        float r2 = __shfl_xor(av, 32);   // t0 lanes: tanh(g)
        float r3 = __shfl_xor(r1, 32);   // t0 lanes: sig(o)

        if (l < 16) {
            c = r1 * c + av * r2;        // c = sig(f)*c + sig(i)*tanh(g)
            float h = r3 * tanh_f(c);
            h_lds[unit] = h;             // own wave's slice -> no 2nd barrier
            int t = dir ? (TT - 1 - s) : s;
            hout[((size_t)(dir * TT + t) * BB + b) * HH + unit] = h;
        }
        xg = xg_next;
    }
}

// ---------------------------------------------------------------------------
// Kernel 5: head — logits, softmax, argmax, chosen policy. One wave per row.
// ---------------------------------------------------------------------------
__global__ __launch_bounds__(256) void head_k(
    const float* __restrict__ hbuf,           // [2][T][B][H]
    const float* __restrict__ wout, const float* __restrict__ bout,
    float* __restrict__ out)
{
    int wid  = threadIdx.x >> 6;
    int lane = threadIdx.x & 63;
    int row  = blockIdx.x * 4 + wid;          // t*64+b, 0..8191
    int t = row >> 6, b = row & 63;
    const float* hf = hbuf + ((size_t)(t)      * BB + b) * HH;
    const float* hb = hbuf + ((size_t)(TT + t) * BB + b) * HH;

    float l0 = 0.f, l1 = 0.f, v;
    v = hf[lane];      l0 += v * wout[lane];           l1 += v * wout[256 + lane];
    v = hf[lane + 64]; l0 += v * wout[64 + lane];      l1 += v * wout[320 + lane];
    v = hb[lane];      l0 += v * wout[128 + lane];     l1 += v * wout[384 + lane];
    v = hb[lane + 64]; l0 += v * wout[192 + lane];     l1 += v * wout[448 + lane];
#pragma unroll
    for (int off = 32; off > 0; off >>= 1) {
        l0 += __shfl_down(l0, off);
        l1 += __shfl_down(l1, off);
    }
    if (lane == 0) {
        l0 += bout[0]; l1 += bout[1];
        float m  = fmaxf(l0, l1);
        float e0 = __expf(l0 - m), e1 = __expf(l1 - m);
        float inv = 1.f / (e0 + e1);
        float p0 = e0 * inv, p1 = e1 * inv;
        int amax = (l1 > l0) ? 1 : 0;          // tie -> 0, matches jnp.argmax
        out[(size_t)row * 2 + 0] = l0;
        out[(size_t)row * 2 + 1] = l1;
        out[16384 + (size_t)row * 2 + 0] = p0;
        out[16384 + (size_t)row * 2 + 1] = p1;
        out[32768 + row] = amax ? p1 : p0;
        out[40960 + row] = (float)amax;
    }
}

// ---------------------------------------------------------------------------
// Kernel 6: expand utterance mask to tokens, write masked input as float.
// ---------------------------------------------------------------------------
__global__ __launch_bounds__(256) void mask_k(
    const int* __restrict__ x, const int* __restrict__ seg,
    const float* __restrict__ umask, float* __restrict__ out4)
{
    int idx = blockIdx.x * 256 + threadIdx.x;    // < 131072
    int b = idx & 63;
    int s = seg[idx];
    if (s > TT - 1) s = TT - 1;                  // jnp OOB indexing clamps
    if (s < 0) s = 0;
    float keep = umask[s * BB + b];
    out4[idx] = (keep != 0.f) ? (float)x[idx] : 0.f;
}

// ---------------------------------------------------------------------------
extern "C" void kernel_launch(void* const* d_in, const int* in_sizes, int n_in,
                              void* d_out, int out_size, void* d_ws, size_t ws_size,
                              hipStream_t stream)
{
    const int*   x    = (const int*)  d_in[0];
    const float* emb  = (const float*)d_in[1];
    const float* wihf = (const float*)d_in[2];
    const float* whhf = (const float*)d_in[3];
    const float* bihf = (const float*)d_in[4];
    const float* bhhf = (const float*)d_in[5];
    const float* wihb = (const float*)d_in[6];
    const float* whhb = (const float*)d_in[7];
    const float* bihb = (const float*)d_in[8];
    const float* bhhb = (const float*)d_in[9];
    const float* wout = (const float*)d_in[10];
    const float* bout = (const float*)d_in[11];
    float* out = (float*)d_out;
    char*  ws  = (char*)d_ws;

    // workspace layout (bytes)
    int*   seg   = (int*)  (ws + 0);         // 2048*64*4   = 524288
    int*   cnt   = (int*)  (ws + 524288);    // 128*64*4    = 32768
    int*   start = (int*)  (ws + 557056);    // 32768
    float* up    = (float*)(ws + 589824);    // 128*64*256*4  = 8 MB
    float* xp    = (float*)(ws + 8978432);   // 128*64*1024*4 = 32 MB
    float* hbuf  = (float*)(ws + 42532864);  // 2*128*64*128*4 = 8 MB

    segscan_k<<<64, 256, 0, stream>>>(x, seg, cnt, start);
    pool_k<<<2048, 256, 0, stream>>>(x, emb, cnt, start, up);   // 8192 waves
    xp_gemm_k<<<dim3(128, 16), 256, 0, stream>>>(up, wihf, wihb, bihf, bhhf, bihb, bhhb, xp);
    lstm_rec_k<<<128, 512, 0, stream>>>(xp, whhf, whhb, hbuf);
    head_k<<<2048, 256, 0, stream>>>(hbuf, wout, bout, out);
    mask_k<<<512, 256, 0, stream>>>(x, seg, out + 40960, out + 49152);
}

// Round 12
// 299.083 us; speedup vs baseline: 1.1973x; 1.1973x over previous
//
#include <hip/hip_runtime.h>
#include <math.h>

// Problem constants (from reference)
#define LL   2048     // seq len
#define BB   64       // batch
#define EE   256      // embedding
#define HH   128      // lstm hidden per dir
#define GG   512      // 4*H gates
#define TT   128      // utterances (L / SEP_EVERY)
#define SEPT 50256

// ---------------------------------------------------------------------------
// Kernel 1: per-column prefix-scan of SEP flags -> seg[t,b], plus per-(utt,b)
// token counts and start offsets (segments are contiguous per column).
// ---------------------------------------------------------------------------
__global__ __launch_bounds__(256) void segscan_k(
    const int* __restrict__ x, int* __restrict__ seg,
    int* __restrict__ cnt, int* __restrict__ start)
{
    int b   = blockIdx.x;    // 0..63
    int tid = threadIdx.x;   // 0..255, 8 tokens each
    __shared__ int tsum[256];
    __shared__ int ucnt[TT];
    __shared__ int ustart[TT];

    int flags[8];
    int local = 0;
#pragma unroll
    for (int i = 0; i < 8; i++) {
        int t = tid * 8 + i;
        flags[i] = (x[t * BB + b] == SEPT) ? 1 : 0;
        local += flags[i];
    }
    tsum[tid] = local;
    __syncthreads();
    int val = local;
    for (int off = 1; off < 256; off <<= 1) {
        int other = (tid >= off) ? tsum[tid - off] : 0;
        __syncthreads();
        val += other;
        tsum[tid] = val;
        __syncthreads();
    }
    int excl = val - local;   // seps strictly before this thread's chunk

    if (tid < TT) ucnt[tid] = 0;
    __syncthreads();
    int run = excl;
#pragma unroll
    for (int i = 0; i < 8; i++) {
        int t = tid * 8 + i;
        int s = run;                 // seg id = #seps before this token
        seg[t * BB + b] = s;
        run += flags[i];
        if (s < TT) atomicAdd(&ucnt[s], 1);
    }
    __syncthreads();
    if (tid == 0) {
        int acc = 0;
        for (int u = 0; u < TT; u++) { ustart[u] = acc; acc += ucnt[u]; }
    }
    __syncthreads();
    if (tid < TT) {
        cnt[tid * BB + b]   = ucnt[tid];
        start[tid * BB + b] = ustart[tid];
    }
}

// ---------------------------------------------------------------------------
// Kernel 2: embedding gather + mean pool. One WAVE per (utt,b); lane holds a
// float4 column slice -> one coalesced 1KB row read per token. Grid = 2048.
// ---------------------------------------------------------------------------
__global__ __launch_bounds__(256) void pool_k(
    const int* __restrict__ x, const float* __restrict__ emb,
    const int* __restrict__ cnt, const int* __restrict__ start,
    float* __restrict__ up)
{
    int wid  = threadIdx.x >> 6;
    int lane = threadIdx.x & 63;
    int bid  = blockIdx.x * 4 + wid;   // u*64+b, bid in [0,8192)
    int b    = bid & 63;
    int c    = cnt[bid];
    int st   = start[bid];

    float4 acc = {0.f, 0.f, 0.f, 0.f};
    int tok = (c > 0) ? x[st * BB + b] : 0;
    for (int j = 0; j < c; j++) {
        int tok_n = (j + 1 < c) ? x[(st + j + 1) * BB + b] : 0;  // prefetch
        float4 v = ((const float4*)(emb + (size_t)tok * EE))[lane];
        acc.x += v.x; acc.y += v.y; acc.z += v.z; acc.w += v.w;
        tok = tok_n;
    }
    float inv = (c > 0) ? 1.f / (float)c : 0.f;
    float4 r = {acc.x * inv, acc.y * inv, acc.z * inv, acc.w * inv};
    ((float4*)(up + (size_t)bid * EE))[lane] = r;
}

// ---------------------------------------------------------------------------
// Kernel 3: xp = u @ W_cat^T + (b_ih + b_hh).  fp32 register-tiled GEMM, v2.
// 128x128 tile, 256 threads, 8x8 micro-tile: 16 FMA per ds_read_b128 (was 8).
// Grid (64, 8) = 512 blocks = 2/CU. Compute floor 27 us at 157 TF.
// ---------------------------------------------------------------------------
__global__ __launch_bounds__(256) void xp_gemm_k(
    const float* __restrict__ A,
    const float* __restrict__ wf, const float* __restrict__ wb,
    const float* __restrict__ bihf, const float* __restrict__ bhhf,
    const float* __restrict__ bihb, const float* __restrict__ bhhb,
    float* __restrict__ C)
{
    __shared__ float As[32][128];   // [k][m] 16 KB
    __shared__ float Bs[32][128];   // [k][n] 16 KB
    int tid  = threadIdx.x;
    int row0 = blockIdx.x * 128;    // 64 blocks
    int col0 = blockIdx.y * 128;    // 8 blocks
    int tx = tid & 15, ty = tid >> 4;   // 16 x 16 threads, 8x8 micro
    float acc[8][8] = {};

    for (int k0 = 0; k0 < EE; k0 += 32) {
#pragma unroll
        for (int i = 0; i < 4; i++) {
            int idx = tid + i * 256;       // float4 slot, 1024 total
            int m   = idx >> 3;            // 0..127
            int k4  = idx & 7;             // 0..7
            float4 av = *(const float4*)(A + (size_t)(row0 + m) * EE + k0 + k4 * 4);
            As[k4 * 4 + 0][m] = av.x; As[k4 * 4 + 1][m] = av.y;
            As[k4 * 4 + 2][m] = av.z; As[k4 * 4 + 3][m] = av.w;
        }
#pragma unroll
        for (int i = 0; i < 4; i++) {
            int idx = tid + i * 256;
            int n   = idx >> 3;
            int k4  = idx & 7;
            int gc  = col0 + n;
            const float* wsrc = (gc < GG) ? (wf + (size_t)gc * EE)
                                          : (wb + (size_t)(gc - GG) * EE);
            float4 bv = *(const float4*)(wsrc + k0 + k4 * 4);
            Bs[k4 * 4 + 0][n] = bv.x; Bs[k4 * 4 + 1][n] = bv.y;
            Bs[k4 * 4 + 2][n] = bv.z; Bs[k4 * 4 + 3][n] = bv.w;
        }
        __syncthreads();
#pragma unroll
        for (int k = 0; k < 32; k++) {
            float a8[8], b8[8];
            *(float4*)&a8[0] = *(const float4*)&As[k][ty * 8 + 0];
            *(float4*)&a8[4] = *(const float4*)&As[k][ty * 8 + 4];
            *(float4*)&b8[0] = *(const float4*)&Bs[k][tx * 8 + 0];
            *(float4*)&b8[4] = *(const float4*)&Bs[k][tx * 8 + 4];
#pragma unroll
            for (int i = 0; i < 8; i++)
#pragma unroll
                for (int j = 0; j < 8; j++)
                    acc[i][j] += a8[i] * b8[j];
        }
        __syncthreads();
    }

    // epilogue: bias + float4 stores
    float bias[8];
#pragma unroll
    for (int j = 0; j < 8; j++) {
        int gc = col0 + tx * 8 + j;
        bias[j] = (gc < GG) ? (bihf[gc] + bhhf[gc])
                            : (bihb[gc - GG] + bhhb[gc - GG]);
    }
#pragma unroll
    for (int i = 0; i < 8; i++) {
        int r = row0 + ty * 8 + i;
        float4 v0 = {acc[i][0] + bias[0], acc[i][1] + bias[1],
                     acc[i][2] + bias[2], acc[i][3] + bias[3]};
        float4 v1 = {acc[i][4] + bias[4], acc[i][5] + bias[5],
                     acc[i][6] + bias[6], acc[i][7] + bias[7]};
        *(float4*)(C + (size_t)r * 1024 + col0 + tx * 8 + 0) = v0;
        *(float4*)(C + (size_t)r * 1024 + col0 + tx * 8 + 4) = v1;
    }
}

// ---------------------------------------------------------------------------
// Fast activations
// ---------------------------------------------------------------------------
__device__ __forceinline__ float sigm_f(float x) {
    return 1.f / (1.f + __expf(-x));
}
__device__ __forceinline__ float tanh_f(float x) {
    return 1.f - 2.f / (__expf(2.f * x) + 1.f);
}

// ---------------------------------------------------------------------------
// Kernel 4: LSTM recurrence — r2 structure (fastest measured: 112.5 us,
// SQ_LDS_BANK_CONFLICT=0) + trailing barrier to close r2's latent h race.
//
// FINDINGS (r2-r11): the 512x128 weight matrix (256 KB/block) cannot be made
// arch-VGPR-resident — the backend remat-sinks invariant loads (r2-r9),
// AGPR-spills volatile ones (r10: 162 us, accvgpr_read per use), and the
// explicit-AGPR asm crashed (r11). The step floor is the per-CU L2 inbound
// stream of 256 KB/step ~= 2120 cyc -> ~113 us. r2's padded part[g][9]
// layout measures ZERO bank conflicts (my v4 "swizzle" caused 2.1M).
// So: plain loads (compiler streams them as dwordx4 from L2), padded part,
// 3 barriers/step, no pins/attrs/pads.
// ---------------------------------------------------------------------------
__global__ __launch_bounds__(512, 2) void lstm_rec_k(
    const float* __restrict__ xp,            // [T*B][1024]
    const float* __restrict__ whh_f, const float* __restrict__ whh_b,
    float* __restrict__ hout)                // [2][T][B][H]
{
    int bid = blockIdx.x;
    int dir = bid >> 6;
    int b   = bid & 63;
    int tid = threadIdx.x;
    int wv  = tid >> 6;      // wave id 0..7 -> k-slice
    int l   = tid & 63;      // lane -> gate set {l + 64j}
    const float* whh = dir ? whh_b : whh_f;

    // weights: w[j][k] = whh[(l+64j)*128 + 16*wv + k]
    float w[8][16];
#pragma unroll
    for (int j = 0; j < 8; j++) {
        const float* src = whh + (size_t)(l + 64 * j) * HH + 16 * wv;
#pragma unroll
        for (int k4 = 0; k4 < 4; k4++) {
            float4 wv4 = *(const float4*)(src + k4 * 4);
            w[j][k4 * 4 + 0] = wv4.x; w[j][k4 * 4 + 1] = wv4.y;
            w[j][k4 * 4 + 2] = wv4.z; w[j][k4 * 4 + 3] = wv4.w;
        }
    }

    __shared__ __align__(16) float h_lds[HH];
    __shared__ float part[GG][9];   // [gate][wave], pad 9 -> 0 conflicts (r2)
    __shared__ float act[GG];

    int g    = tid;                 // gate this thread reduces in phase 2
    int sect = g >> 7;              // 0:i 1:f 2:g 3:o (wave-uniform)

    float c = 0.f;                  // cell state (threads < 128)
    if (g < HH) h_lds[g] = 0.f;
    __syncthreads();

    int t0   = dir ? (TT - 1) : 0;
    float xg = xp[(size_t)(t0 * BB + b) * 1024 + dir * GG + g];

    for (int s = 0; s < TT; s++) {
        // ---- phase 1: partial dots over this wave's k-slice ----
        float hs[16];
#pragma unroll
        for (int k4 = 0; k4 < 4; k4++)
            *(float4*)&hs[k4 * 4] = *(const float4*)&h_lds[wv * 16 + k4 * 4];

        float acc[8] = {0.f, 0.f, 0.f, 0.f, 0.f, 0.f, 0.f, 0.f};
#pragma unroll
        for (int k = 0; k < 16; k++) {
            float hk = hs[k];
#pragma unroll
            for (int j = 0; j < 8; j++)
                acc[j] += w[j][k] * hk;
        }

        // prefetch next step's xp while FMAs drain
        float xg_next = xg;
        if (s < TT - 1) {
            int tn = dir ? (TT - 2 - s) : (s + 1);
            xg_next = xp[(size_t)(tn * BB + b) * 1024 + dir * GG + g];
        }

#pragma unroll
        for (int j = 0; j < 8; j++)
            part[l + 64 * j][wv] = acc[j];
        __syncthreads();

        // ---- phase 2: reduce partials for gate g, activate ----
        float sum = xg;
#pragma unroll
        for (int w2 = 0; w2 < 8; w2++)
            sum += part[g][w2];
        act[g] = (sect == 2) ? tanh_f(sum) : sigm_f(sum);
        __syncthreads();

        // ---- phase 3: c/h update for hidden unit tid (<128) ----
        if (tid < HH) {
            float si = act[tid], sf = act[HH + tid];
            float tg = act[2 * HH + tid], so = act[3 * HH + tid];
            c = sf * c + si * tg;
            float h = so * tanh_f(c);
            h_lds[tid] = h;
            int t = dir ? (TT - 1 - s) : s;
            hout[((size_t)(dir * TT + t) * BB + b) * HH + tid] = h;
        }
        xg = xg_next;
        __syncthreads();   // close r2's h_lds race (phase-3 write vs next phase-1 read)
    }
}

// ---------------------------------------------------------------------------
// Kernel 5: head — logits, softmax, argmax, chosen policy. One wave per row.
// ---------------------------------------------------------------------------
__global__ __launch_bounds__(256) void head_k(
    const float* __restrict__ hbuf,           // [2][T][B][H]
    const float* __restrict__ wout, const float* __restrict__ bout,
    float* __restrict__ out)
{
    int wid  = threadIdx.x >> 6;
    int lane = threadIdx.x & 63;
    int row  = blockIdx.x * 4 + wid;          // t*64+b, 0..8191
    int t = row >> 6, b = row & 63;
    const float* hf = hbuf + ((size_t)(t)      * BB + b) * HH;
    const float* hb = hbuf + ((size_t)(TT + t) * BB + b) * HH;

    float l0 = 0.f, l1 = 0.f, v;
    v = hf[lane];      l0 += v * wout[lane];           l1 += v * wout[256 + lane];
    v = hf[lane + 64]; l0 += v * wout[64 + lane];      l1 += v * wout[320 + lane];
    v = hb[lane];      l0 += v * wout[128 + lane];     l1 += v * wout[384 + lane];
    v = hb[lane + 64]; l0 += v * wout[192 + lane];     l1 += v * wout[448 + lane];
#pragma unroll
    for (int off = 32; off > 0; off >>= 1) {
        l0 += __shfl_down(l0, off);
        l1 += __shfl_down(l1, off);
    }
    if (lane == 0) {
        l0 += bout[0]; l1 += bout[1];
        float m  = fmaxf(l0, l1);
        float e0 = __expf(l0 - m), e1 = __expf(l1 - m);
        float inv = 1.f / (e0 + e1);
        float p0 = e0 * inv, p1 = e1 * inv;
        int amax = (l1 > l0) ? 1 : 0;          // tie -> 0, matches jnp.argmax
        out[(size_t)row * 2 + 0] = l0;
        out[(size_t)row * 2 + 1] = l1;
        out[16384 + (size_t)row * 2 + 0] = p0;
        out[16384 + (size_t)row * 2 + 1] = p1;
        out[32768 + row] = amax ? p1 : p0;
        out[40960 + row] = (float)amax;
    }
}

// ---------------------------------------------------------------------------
// Kernel 6: expand utterance mask to tokens, write masked input as float.
// ---------------------------------------------------------------------------
__global__ __launch_bounds__(256) void mask_k(
    const int* __restrict__ x, const int* __restrict__ seg,
    const float* __restrict__ umask, float* __restrict__ out4)
{
    int idx = blockIdx.x * 256 + threadIdx.x;    // < 131072
    int b = idx & 63;
    int s = seg[idx];
    if (s > TT - 1) s = TT - 1;                  // jnp OOB indexing clamps
    if (s < 0) s = 0;
    float keep = umask[s * BB + b];
    out4[idx] = (keep != 0.f) ? (float)x[idx] : 0.f;
}

// ---------------------------------------------------------------------------
extern "C" void kernel_launch(void* const* d_in, const int* in_sizes, int n_in,
                              void* d_out, int out_size, void* d_ws, size_t ws_size,
                              hipStream_t stream)
{
    const int*   x    = (const int*)  d_in[0];
    const float* emb  = (const float*)d_in[1];
    const float* wihf = (const float*)d_in[2];
    const float* whhf = (const float*)d_in[3];
    const float* bihf = (const float*)d_in[4];
    const float* bhhf = (const float*)d_in[5];
    const float* wihb = (const float*)d_in[6];
    const float* whhb = (const float*)d_in[7];
    const float* bihb = (const float*)d_in[8];
    const float* bhhb = (const float*)d_in[9];
    const float* wout = (const float*)d_in[10];
    const float* bout = (const float*)d_in[11];
    float* out = (float*)d_out;
    char*  ws  = (char*)d_ws;

    // workspace layout (bytes)
    int*   seg   = (int*)  (ws + 0);         // 2048*64*4   = 524288
    int*   cnt   = (int*)  (ws + 524288);    // 128*64*4    = 32768
    int*   start = (int*)  (ws + 557056);    // 32768
    float* up    = (float*)(ws + 589824);    // 128*64*256*4  = 8 MB
    float* xp    = (float*)(ws + 8978432);   // 128*64*1024*4 = 32 MB
    float* hbuf  = (float*)(ws + 42532864);  // 2*128*64*128*4 = 8 MB

    segscan_k<<<64, 256, 0, stream>>>(x, seg, cnt, start);
    pool_k<<<2048, 256, 0, stream>>>(x, emb, cnt, start, up);   // 8192 waves
    xp_gemm_k<<<dim3(64, 8), 256, 0, stream>>>(up, wihf, wihb, bihf, bhhf, bihb, bhhb, xp);
    lstm_rec_k<<<128, 512, 0, stream>>>(xp, whhf, whhb, hbuf);
    head_k<<<2048, 256, 0, stream>>>(hbuf, wout, bout, out);
    mask_k<<<512, 256, 0, stream>>>(x, seg, out + 40960, out + 49152);
}